// Round 1
// baseline (215.739 us; speedup 1.0000x reference)
//
#include <hip/hip_runtime.h>

// Problem constants (B=16, D=128, H=32, W=32, K=8192)
#define D 128
#define HW 1024
#define NROWS 16384
#define K 8192
#define NU 32   // 64-col units per block (2048-col k-split / 64)

// d_out layout (float offsets): z_q_st | indices | new_codebook | new_count | new_weight
#define OUT0 0
#define OUT1 2097152
#define OUT2 2113536
#define OUT3 3162112
#define OUT4 3170304

typedef __attribute__((ext_vector_type(8))) _Float16 half8;
typedef __attribute__((ext_vector_type(16))) float f32x16;
typedef unsigned short u16;
typedef unsigned long long u64;

// ---- async global->LDS, 16B per lane (dst = wave-uniform base + lane*16) ----
__device__ __forceinline__ void gld16(const u16* gsrc, u16* ldst) {
    __builtin_amdgcn_global_load_lds(
        (const __attribute__((address_space(1))) unsigned int*)gsrc,
        (__attribute__((address_space(3))) unsigned int*)ldst,
        16, 0, 0);
}

// ---- fused prep: blocks [0,512) codebook-split + cnorm + dw-zero;
//      blocks [512,1536) z-split + packed-init + counts-zero ----
// B layout: [unit g(128)][ Bh: [kk(16)][col(64)][j(8)] | Bl: same ] (32 KiB/unit)
// A layout: [band(n>>5)][ks(8)][lh(2)][row(32)][j(8)]  (same linear order as before)
__global__ __launch_bounds__(256) void k_prep(const float* __restrict__ cb,
                                              const float* __restrict__ z_e,
                                              u16* __restrict__ Bg,
                                              float* __restrict__ cnorm,
                                              u16* __restrict__ Ah, u16* __restrict__ Al,
                                              u64* __restrict__ packed,
                                              float* __restrict__ counts,
                                              float* __restrict__ dw) {
    const int tid = threadIdx.x;
    if (blockIdx.x < 512) {
        int kk = tid & 15;
        int k = blockIdx.x * 16 + (tid >> 4);
        const float* src = cb + (size_t)k * D + kk * 8;
        half8 h, l;
        float s = 0.f;
#pragma unroll
        for (int j = 0; j < 8; ++j) {
            float v = src[j];
            s += v * v;
            _Float16 hv = (_Float16)v;              // RN f32->f16
            _Float16 lv = (_Float16)(v - (float)hv);
            h[j] = hv;
            l[j] = lv;
        }
        int g = k >> 6, col = k & 63;
        size_t offH = (size_t)g * 16384 + ((size_t)kk * 64 + col) * 8;
        *(half8*)((_Float16*)Bg + offH) = h;
        *(half8*)((_Float16*)Bg + offH + 8192) = l;
#pragma unroll
        for (int off = 8; off > 0; off >>= 1) s += __shfl_down(s, off);
        if (kk == 0) cnorm[k] = s;
        // zero dw: 131072 threads x 8 floats = K*D exactly
        float4 z4 = {0.f, 0.f, 0.f, 0.f};
        size_t zi = ((size_t)blockIdx.x * 256 + tid) * 8;
        *(float4*)(dw + zi) = z4;
        *(float4*)(dw + zi + 4) = z4;
    } else {
        int gid = (blockIdx.x - 512) * 256 + tid;   // NROWS*16 threads
        int n  = gid & (NROWS - 1);                 // lane-contiguous n -> coalesced
        int kk = gid >> 14;                         // 0..15
        int b = n >> 10, hw = n & 1023;
        const float* src = z_e + ((size_t)b * D + kk * 8) * HW + hw;
        half8 h, l;
#pragma unroll
        for (int j = 0; j < 8; ++j) {
            float v = src[(size_t)j * HW];
            _Float16 hv = (_Float16)v;
            _Float16 lv = (_Float16)(v - (float)hv);
            h[j] = hv;
            l[j] = lv;
        }
        int rg = n >> 7, band = (n >> 5) & 3, row = n & 31;
        size_t off = (((((size_t)rg * 4 + band) * 8 + (kk >> 1)) * 2 + (kk & 1)) * 32 + row) * 8;
        *(half8*)(Ah + off) = h;
        *(half8*)(Al + off) = l;
        if (kk == 0) {
            packed[n] = ~0ull;                      // +inf sentinel
            if (n < K) counts[n] = 0.f;
        }
    }
}

// ---- main: 3-pass fp16-split distance GEMM + fused argmin ----
// grid: 64 rowgroups (256 rows) x 4 ksplits = 256 blocks (1/CU), 512 threads
// (8 waves: wy 0..3 x wx 0..1). Wave tile: 64 rows (2 row-tiles) x 32 cols.
// Ah pinned in regs (64); Al staged ONCE into a 64 KiB LDS slab (frees 64 regs
// of lookahead for the compiler's ds_read pipelining). B in 64-col units,
// 2x32 KiB LDS dbuf with in-flight prefetch across raw s_barrier via vmcnt(4).
// Every B fragment feeds 4 MFMAs (2 row-tiles; bh shared by passes 2+3).
__global__ __launch_bounds__(512, 2) void k_argmin_mfma(
        const u16* __restrict__ Ahg, const u16* __restrict__ Alg,
        const u16* __restrict__ Bg,
        const float* __restrict__ cnorm, u64* __restrict__ packed) {
    extern __shared__ u16 smem[];                 // 128 KiB dynamic
    u16* Bb0 = smem;                              // 32 KiB
    u16* Bb1 = smem + 16384;                      // 32 KiB
    u16* AlS = smem + 32768;                      // 64 KiB Al slab (this rowgroup)

    const int tid = threadIdx.x;
    const int ln  = tid & 63;
    const int l31 = ln & 31;
    const int lh  = ln >> 5;                    // k-half select within frag
    const int wv  = tid >> 6;                   // 0..7
    const int wy  = wv & 3;                     // row band pair 0..3
    const int wx  = wv >> 2;                    // col half 0..1

    const int rg = blockIdx.x >> 2;             // 64 row groups x 256 rows
    const int k0 = (blockIdx.x & 3) * 2048;     // k split
    const int g0 = k0 >> 6;                     // first 64-col B-unit
    const int t0 = wy * 2;                      // wave's first 32-row tile (0..7)

    // ---- A-high fragments -> registers (read once; 64 regs) ----
    half8 Ah0[8], Ah1[8];
#pragma unroll
    for (int ks = 0; ks < 8; ++ks) {
        size_t o0 = ((((size_t)(rg * 8 + t0)     * 8 + ks) * 2 + lh) * 32 + l31) * 8;
        size_t o1 = ((((size_t)(rg * 8 + t0 + 1) * 8 + ks) * 2 + lh) * 32 + l31) * 8;
        Ah0[ks] = *(const half8*)((const _Float16*)Ahg + o0);
        Ah1[ks] = *(const half8*)((const _Float16*)Ahg + o1);
    }

    // ---- prologue: stage Al slab (64 KiB) + B unit 0 (32 KiB) ----
    {
        const u16* srcA = Alg + (size_t)rg * 32768;   // 256 rows x 128 halfs
#pragma unroll
        for (int r = 0; r < 8; ++r)
            gld16(srcA + ((size_t)r * 512 + tid) * 8, AlS + (r * 512 + tid) * 8);
        const u16* srcB = Bg + (size_t)g0 * 16384;
#pragma unroll
        for (int r = 0; r < 4; ++r)
            gld16(srcB + ((size_t)r * 512 + tid) * 8, Bb0 + (r * 512 + tid) * 8);
    }

    float minv[32];
    int   mini[32];
#pragma unroll
    for (int r = 0; r < 32; ++r) { minv[r] = INFINITY; mini[r] = 0; }

#pragma unroll 1
    for (int u = 0; u < NU; ++u) {
        const u16* buf = (u & 1) ? Bb1 : Bb0;
        const int c0 = k0 + u * 64 + wx * 32 + l31;

        // cn load first (older than the prefetch -> completed once vmcnt<=4)
        float cn0 = cnorm[c0];

        if (u + 1 < NU) {
            const u16* src = Bg + (size_t)(g0 + u + 1) * 16384;
            u16* dst = (u & 1) ? Bb0 : Bb1;
#pragma unroll
            for (int r = 0; r < 4; ++r)
                gld16(src + ((size_t)r * 512 + tid) * 8, dst + (r * 512 + tid) * 8);
            // wait for *this* unit's stage; next unit's 4 loads stay in flight
            asm volatile("s_waitcnt vmcnt(4)" ::: "memory");
        } else {
            asm volatile("s_waitcnt vmcnt(0)" ::: "memory");
        }
        asm volatile("s_barrier" ::: "memory");

        f32x16 acc0 = {}, acc1 = {};
        const _Float16* bh = (const _Float16*)buf;
        const _Float16* bl = bh + 8192;
        const _Float16* al = (const _Float16*)AlS;

        __builtin_amdgcn_s_setprio(1);
        // pass 1: Ah x Bl (b-frag shared by both row-tiles)
#pragma unroll
        for (int ks = 0; ks < 8; ++ks) {
            const int bo = ((ks * 2 + lh) * 64 + wx * 32 + l31) * 8;
            half8 b0 = *(const half8*)(bl + bo);
            acc0 = __builtin_amdgcn_mfma_f32_32x32x16_f16(Ah0[ks], b0, acc0, 0, 0, 0);
            acc1 = __builtin_amdgcn_mfma_f32_32x32x16_f16(Ah1[ks], b0, acc1, 0, 0, 0);
        }
        // passes 2+3: Ah x Bh, Al x Bh (b-frag shared 4 ways)
#pragma unroll
        for (int ks = 0; ks < 8; ++ks) {
            const int bo = ((ks * 2 + lh) * 64 + wx * 32 + l31) * 8;
            half8 b0 = *(const half8*)(bh + bo);
            half8 a0 = *(const half8*)(al + ((((t0)     * 8 + ks) * 2 + lh) * 32 + l31) * 8);
            half8 a1 = *(const half8*)(al + ((((t0 + 1) * 8 + ks) * 2 + lh) * 32 + l31) * 8);
            acc0 = __builtin_amdgcn_mfma_f32_32x32x16_f16(Ah0[ks], b0, acc0, 0, 0, 0);
            acc1 = __builtin_amdgcn_mfma_f32_32x32x16_f16(Ah1[ks], b0, acc1, 0, 0, 0);
            acc0 = __builtin_amdgcn_mfma_f32_32x32x16_f16(a0, b0, acc0, 0, 0, 0);
            acc1 = __builtin_amdgcn_mfma_f32_32x32x16_f16(a1, b0, acc1, 0, 0, 0);
        }
        __builtin_amdgcn_s_setprio(0);

        // fold dist = cnorm - 2*dot into running argmin (both row-tiles)
#pragma unroll
        for (int r = 0; r < 16; ++r) {
            float d0 = fmaf(-2.0f, acc0[r], cn0);
            float d1 = fmaf(-2.0f, acc1[r], cn0);
            if (d0 < minv[r])      { minv[r]      = d0; mini[r]      = c0; }
            if (d1 < minv[16 + r]) { minv[16 + r] = d1; mini[16 + r] = c0; }
        }
        // all waves done reading buf before its sibling is overwritten next iter
        asm volatile("s_barrier" ::: "memory");
    }

    // ---- reduce across the 32 l31-lanes sharing each output row ----
#pragma unroll
    for (int t = 0; t < 2; ++t) {
#pragma unroll
        for (int r = 0; r < 16; ++r) {
            float v = minv[t * 16 + r];
            int ix = mini[t * 16 + r];
#pragma unroll
            for (int off = 1; off < 32; off <<= 1) {
                float v2 = __shfl_xor(v, off);
                int i2 = __shfl_xor(ix, off);
                if (v2 < v || (v2 == v && i2 < ix)) { v = v2; ix = i2; }
            }
            if (l31 == 0) {
                // C/D row map (m74/m101): row = (reg&3) + 8*(reg>>2) + 4*(lane>>5)
                int row = rg * 256 + (t0 + t) * 32 + 4 * lh + (r & 3) + 8 * (r >> 2);
                unsigned int uenc = __float_as_uint(v);
                uenc = (uenc & 0x80000000u) ? ~uenc : (uenc | 0x80000000u);  // monotonic
                u64 pk = ((u64)uenc << 13) | (u64)(unsigned)ix;
                atomicMin(&packed[row], pk);
            }
        }
    }
}

// ---- epilogue: indices, z_q_st, counts, dw ----
__global__ __launch_bounds__(256) void k_epilogue(const float* __restrict__ z_e,
                                                  const float* __restrict__ cb,
                                                  const u64* __restrict__ packed,
                                                  float* __restrict__ out0,
                                                  float* __restrict__ out1,
                                                  float* __restrict__ counts,
                                                  float* __restrict__ dw) {
    __shared__ int idxS[64];
    const int tid = threadIdx.x;
    const int n0 = blockIdx.x * 64;
    const int bb = n0 >> 10, p0 = n0 & 1023;

    if (tid < 64) {
        int ix = (int)(packed[n0 + tid] & 0x1FFFull);
        idxS[tid] = ix;
        out1[n0 + tid] = (float)ix;
        atomicAdd(&counts[ix], 1.0f);
    }
    __syncthreads();

    const float* zb = z_e + (size_t)bb * (D * HW) + p0;
    float* ob = out0 + (size_t)bb * (D * HW) + p0;

    for (int i = tid; i < 64 * D; i += 256) {
        int d = i >> 6, r = i & 63;
        float z = zb[(size_t)d * HW + r];
        float c = cb[(size_t)idxS[r] * D + d];
        ob[(size_t)d * HW + r] = z + (c - z);
    }
    for (int i = tid; i < 64 * D; i += 256) {
        int r = i >> 7, d = i & 127;
        atomicAdd(&dw[(size_t)idxS[r] * D + d], zb[(size_t)d * HW + r]);
    }
}

__global__ __launch_bounds__(256) void k_final(const float* __restrict__ ema_count,
                                               const float* __restrict__ ema_weight,
                                               float* __restrict__ out2,
                                               float* __restrict__ out3,
                                               float* __restrict__ out4) {
    int gid = blockIdx.x * 256 + threadIdx.x;   // over K*D
    int k = gid >> 7, d = gid & 127;
    float cnt_raw = out3[k];
    float dw_raw = out4[gid];
    __syncthreads();
    float nc = 0.99f * ema_count[k] + 0.01f * cnt_raw;
    float nw = 0.99f * ema_weight[gid] + 0.01f * dw_raw;
    out4[gid] = nw;
    out2[gid] = nw / fmaxf(nc, 1.0f);
    if (d == 0) out3[k] = nc;
}

extern "C" void kernel_launch(void* const* d_in, const int* in_sizes, int n_in,
                              void* d_out, int out_size, void* d_ws, size_t ws_size,
                              hipStream_t stream) {
    const float* z_e        = (const float*)d_in[0];
    const float* cb         = (const float*)d_in[1];
    const float* ema_count  = (const float*)d_in[2];
    const float* ema_weight = (const float*)d_in[3];
    float* out = (float*)d_out;

    float* cnorm = (float*)d_ws;                                   // K floats
    u64* packed = (u64*)((char*)d_ws + K * 4);                     // NROWS u64

    // fp16-split scratch lives in out regions rewritten later:
    // out0 (8 MB) hosts Ah|Al, out2 (4 MB) hosts the unit-interleaved B.
    u16* Ahg = (u16*)(out + OUT0);
    u16* Alg = Ahg + (size_t)NROWS * D;
    u16* Bg  = (u16*)(out + OUT2);                                 // 128 units x 32 KiB

    // one-time: allow 128 KiB dynamic LDS for the main kernel (host-side, graph-safe)
    static bool attr_done = false;
    if (!attr_done) {
        hipFuncSetAttribute(reinterpret_cast<const void*>(k_argmin_mfma),
                            hipFuncAttributeMaxDynamicSharedMemorySize, 131072);
        attr_done = true;
    }

    k_prep       <<<1536,          256, 0,      stream>>>(cb, z_e, Bg, cnorm, Ahg, Alg,
                                                          packed, out + OUT3, out + OUT4);
    k_argmin_mfma<<<256,           512, 131072, stream>>>(Ahg, Alg, Bg, cnorm, packed);
    k_epilogue   <<<NROWS / 64,    256, 0,      stream>>>(z_e, cb, packed,
                                                          out + OUT0, out + OUT1,
                                                          out + OUT3, out + OUT4);
    k_final      <<<(K * D) / 256, 256, 0,      stream>>>(ema_count, ema_weight,
                                                          out + OUT2, out + OUT3, out + OUT4);
}